// Round 11
// baseline (20.301 us; speedup 1.0000x reference)
//
#include <hip/hip_runtime.h>
#include <math.h>

// ECT layer: ect[b,t,r] = sum_{n: batch[n]==b} sigmoid(8*(lin[r] - <x_n,v_t>))
// N=100000, D=3, T=64, R=64, B=128, lin = linspace(-1.1,1.1,64), d = 2.2/63.
//
// Validated core (r4-r9): CIC-deposit nh onto lin-aligned grid, convolve with
// compile-time sigmoid taps. r7: u32 LDS atomics (f32 LDS atomics are a slow
// serial FP-RMW path on gfx950; 4x). r8: const-literal taps + ds_read2.
// r9: packed u64 deposits. r10 additions: seg precompute (no lb64 gathers),
// saturated-tap window via per-row suffix scan (148 -> 88 real taps).
//
// r10 FAILURE root cause (fixed here): suffix-scan results were passed to
// the conv phase through LDS (Slds) with no barrier, relying on same-wave
// DS ordering. But LLVM reasons PER-THREAD: each lane's Slds write addrs
// (lane, 64+lane) and read addr (lane+60) are provably different per-lane,
// so the compiler saw no dependence and could hoist the ds_read above the
// ds_write -> stale/poisoned LDS (absmax 1.7e32). Cross-lane LDS dataflow
// REQUIRES a barrier (compiler + HW). Fix: __syncthreads() between the
// suffix-scan writes and the conv reads.

#define THREADS 256
#define TPB 4            // directions per block
#define TQ  16           // blocks per point cloud: TPB*TQ = 64 directions
#define PAD 63
#define STEPS 148        // taps: out[r] = sum_{j<148} w[j]*H[r+j]
#define J0 60            // taps j<J0 treated as exactly 1.0 (window sum)
#define ROW32 256        // f32/u32 elements per histogram row (4x64 chunks)
#define ROW64 128        // u64 words per row
#define HO_BASE64 (TPB * ROW64)   // Ho array offset in u64 words
#define BSEG 128

// ---- compile-time sigmoid tap table (folded 2^-16 fixed-point unscale) ----
constexpr double cexp_taylor(double r) {
    double s = 1.0, term = 1.0;
    for (int i = 1; i < 18; ++i) { term *= r / (double)i; s += term; }
    return s;
}
constexpr double cexp(double x) {             // |x| < 45
    const double LN2 = 0.69314718055994530942;
    const int n = (int)(x / LN2 + (x >= 0.0 ? 0.5 : -0.5));
    const double r = x - (double)n * LN2;
    double e = cexp_taylor(r);
    if (n >= 0) { for (int i = 0; i < n;  ++i) e *= 2.0; }
    else        { for (int i = 0; i < -n; ++i) e *= 0.5; }
    return e;
}
struct WTab {
    float w[STEPS];
    constexpr WTab() : w() {
        const double d = 2.2 / 63.0;
        for (int j = 0; j < STEPS; ++j) {
            const double z = 8.0 * d * (double)(111 - j);   // sigmoid argument
            w[j] = (float)(1.0 / ((1.0 + cexp(-z)) * 65536.0));
        }
    }
};
constexpr WTab WT;   // WT.w[j] folds as inline literals in unrolled fmas

// inclusive suffix sum within a 64-lane wave: x_i = sum_{k>=i} x_k
__device__ __forceinline__ float wave_suffix(float x, int lane) {
#pragma unroll
    for (int d = 1; d < 64; d <<= 1) {
        const float y = __shfl_down(x, d, 64);
        x += (lane + d < 64) ? y : 0.0f;
    }
    return x;
}

// --- K0: seg[b] = first node index with batch >= b; seg[BSEG] = n ---
__global__ void seg_bounds_kernel(const int* __restrict__ batch,
                                  int* __restrict__ seg, int n) {
    int i = blockIdx.x * blockDim.x + threadIdx.x;
    if (i >= n) return;
    const int a = batch[i];
    if (i == 0) {
        for (int bb = 0; bb <= a; ++bb) seg[bb] = 0;
    } else {
        const int p = batch[i - 1];
        for (int bb = p + 1; bb <= a; ++bb) seg[bb] = i;
    }
    if (i == n - 1) {
        for (int bb = a + 1; bb <= BSEG; ++bb) seg[bb] = n;
    }
}

__global__ __launch_bounds__(THREADS, 8) void ect_fused8_kernel(
    const float* __restrict__ x,      // [N,3]
    const float* __restrict__ v,      // [3,64]
    const int*   __restrict__ seg,    // [BSEG+1]
    float* __restrict__ out,          // [128,64,64]
    float inv_d, float bias)
{
    __shared__ unsigned long long Hu[2 * TPB * ROW64];   // He rows | Ho rows
    __shared__ float Slds[TPB][128];                     // suffix sums S[0..127]

    const int tid  = threadIdx.x;
    const int wv   = tid >> 6;                   // wave 0..3
    const int lane = tid & 63;
    const int b    = blockIdx.x >> 4;            // / TQ
    const int tq   = blockIdx.x & (TQ - 1);

    // zero both histogram arrays (1024 u64 / 256 threads = 4 ds_write_b64)
    for (int i = tid; i < 2 * TPB * ROW64; i += THREADS) Hu[i] = 0ull;

    // segment bounds: uniform scalar loads (seg precomputed by K0)
    const int s0 = seg[b], s1 = seg[b + 1];

    // deposit mapping: lane = (t_l, slot); block covers 64 nodes/iter
    const int t_l  = lane >> 4;                  // direction 0..3 within block
    const int slot = (lane & 15) + (wv << 4);    // node slot 0..63 across waves
    const int tbase = tq * TPB;
    const int t    = tbase + t_l;
    const float va = v[t], vb = v[64 + t], vc = v[128 + t];
    const int rowoff64 = t_l * ROW64;

    __syncthreads();

    // ---- phase 1: CIC deposit, ONE packed u64 atomic per (node,dir), ----
    // ---- 4-deep preload (256 nodes per outer iteration)              ----
    for (int base = s0; base < s1; base += 4 * 64) {
        float xs0[4], xs1[4], xs2[4];
        bool  ok[4];
#pragma unroll
        for (int k = 0; k < 4; ++k) {
            const int idx = base + (k << 6) + slot;
            ok[k] = (idx < s1);
            if (ok[k]) {
                const float3 xx = *(const float3*)(x + 3 * (size_t)idx);
                xs0[k] = xx.x; xs1[k] = xx.y; xs2[k] = xx.z;
            }
        }
#pragma unroll
        for (int k = 0; k < 4; ++k) {
            if (!ok[k]) continue;
            const float nh = fmaf(xs0[k], va, fmaf(xs1[k], vb, xs2[k] * vc));
            float bin = fmaf(nh, inv_d, bias);           // (nh - umin)/d
            bin = fminf(fmaxf(bin, 0.0f), 158.999f);     // tails saturate
            const float g0f = floorf(bin);
            const float fr  = bin - g0f;
            const int   a   = PAD + (int)g0f;            // 63..221
            const unsigned q1 = (unsigned)(fr * 65536.0f + 0.5f);
            const unsigned q0 = 65536u - q1;
            const unsigned long long val =
                (unsigned long long)q0 | ((unsigned long long)q1 << 32);
            // parity-staggered word: even a -> He[a/2], odd a -> Ho[(a-1)/2]
            const int w64 = (a >> 1) + rowoff64 + ((a & 1) ? HO_BASE64 : 0);
            atomicAdd(&Hu[w64], val);                    // ds_add_u64
        }
    }

    __syncthreads();

    // ---- phase 1.5: reconstruct + u32->f32 in place over He region ----
    // H[a] = He32[a] + Ho32[a-1]; 2^-16 scale folded into taps/window.
    {
        unsigned* He32 = (unsigned*)Hu;
        unsigned* Ho32 = (unsigned*)(Hu + HO_BASE64);
        for (int i = tid; i < TPB * ROW32; i += THREADS) {
            const int a = i & (ROW32 - 1);
            unsigned s = He32[i];
            if (a > 0) s += Ho32[i - 1];
            ((float*)He32)[i] = (float)s;
        }
    }

    __syncthreads();

    // ---- phase 1.75: per-row suffix sums S[0..127] (wave owns row wv) ----
    {
        const float* HF = (const float*)Hu + wv * ROW32;
        const float c0 = HF[lane],       c1 = HF[64 + lane];
        const float c2 = HF[128 + lane], c3 = HF[192 + lane];
        float tot23 = c2 + c3;
#pragma unroll
        for (int d = 1; d < 64; d <<= 1) tot23 += __shfl_xor(tot23, d, 64);
        const float s1v = wave_suffix(c1, lane) + tot23;
        const float carry = __shfl(s1v, 0, 64);
        const float s0v = wave_suffix(c0, lane) + carry;
        Slds[wv][lane]      = s0v;
        Slds[wv][64 + lane] = s1v;
    }

    // REQUIRED: cross-lane dataflow through LDS. Without this barrier the
    // compiler (per-thread alias analysis: write addrs lane/64+lane vs read
    // addr lane+60 provably disjoint) may hoist the reads above the writes.
    __syncthreads();

    // ---- phase 2: conv. wave wv -> direction row wv; lane -> r ----
    const float* H = (const float*)Hu + wv * ROW32 + lane;   // single base VGPR
    // saturated-tap window: sum_{j<J0} H[r+j] = S[r] - S[r+J0], taps == 1.0
    float a0 = (Slds[wv][lane] - Slds[wv][lane + J0]) * (1.0f / 65536.0f);
    float a1 = 0.f;
#pragma unroll
    for (int j = J0; j < STEPS; j += 2) {
        a0 = fmaf(WT.w[j],     H[j],     a0);      // literal * ds_read2.lo
        a1 = fmaf(WT.w[j + 1], H[j + 1], a1);      // literal * ds_read2.hi
    }
    out[((size_t)b * 64 + tbase + wv) * 64 + lane] = a0 + a1;
}

extern "C" void kernel_launch(void* const* d_in, const int* in_sizes, int n_in,
                              void* d_out, int out_size, void* d_ws, size_t ws_size,
                              hipStream_t stream) {
    const float* x     = (const float*)d_in[0];
    const float* v     = (const float*)d_in[1];
    const int*   batch = (const int*)d_in[2];
    float*       out   = (float*)d_out;

    const int n = in_sizes[0] / 3;

    int* seg = (int*)d_ws;   // seg[129] in workspace, fully rewritten each call

    const double d = 2.2 / 63.0;
    const float inv_d = (float)(1.0 / d);          // 28.63636...
    const float bias  = 79.5f;                     // 31.5 + 48, exact

    hipLaunchKernelGGL(seg_bounds_kernel, dim3((n + THREADS - 1) / THREADS),
                       dim3(THREADS), 0, stream, batch, seg, n);
    hipLaunchKernelGGL(ect_fused8_kernel, dim3(BSEG * TQ), dim3(THREADS), 0,
                       stream, x, v, seg, out, inv_d, bias);
}

// Round 12
// 17.803 us; speedup vs baseline: 1.1403x; 1.1403x over previous
//
#include <hip/hip_runtime.h>
#include <math.h>

// ECT layer: ect[b,t,r] = sum_{n: batch[n]==b} sigmoid(8*(lin[r] - <x_n,v_t>))
// N=100000, D=3, T=64, R=64, B=128, lin = linspace(-1.1,1.1,64), d = 2.2/63.
//
// Validated core: CIC-deposit nh onto lin-aligned grid (exact linear split,
// error <= sig''*d^2/8 ~ 9.4e-4/node), convolve with compile-time sigmoid
// taps. r7: u32 LDS atomics (f32 LDS atomics = slow serial FP-RMW on gfx950,
// 4x). r8: const-literal taps + ds_read2. r9: packed u64 deposits.
// r11 lesson: an extra dispatch costs ~5us (launch + graph drain) - more
// than the lb64 it replaced. This round is SINGLE dispatch again:
//  - seg bounds via scalar WINDOWED binary search: guess b*n/128, +-1024
//    (6 sigma) window validated by 2 scalar loads (fallback to full range
//    if violated), then 11 uniform iterations; readfirstlane forces the
//    s_load chain. No vector gathers, no helper kernel.
//  - J0=64: the saturated-tap window becomes PURE-REGISTER: window =
//    S[lane]-S[lane+64] = s0v - s1v, both produced in-lane by the two
//    half-row suffix scans. Slds + its barrier (r10's hazard site) deleted.
//  - reconstruct (He+Ho -> f32) merged into the scan phase, per-wave own
//    row, in place (chunk read/write sets disjoint -> no extra barrier);
//    chunk 0 never converted (conv only reads indices >= J0).
// 3 barriers total, 1 dispatch, no ws, no memset, no global atomics.

#define THREADS 256
#define TPB 4            // directions per block (1 per wave)
#define TQ  16           // blocks per point cloud: TPB*TQ = 64 directions
#define PAD 63
#define J0  64           // taps j<J0 == 1.0 exactly (1-sigma(13.4)=1.5e-6)
#define STEPS 144        // taps: j in [J0, STEPS) real fmas (80 taps)
#define ROW32 256        // f32/u32 elements per histogram row
#define ROW64 128        // u64 words per row
#define HO_BASE64 (TPB * ROW64)   // Ho array offset in u64 words
#define BSEG 128

// ---- compile-time sigmoid tap table (folded 2^-16 fixed-point unscale) ----
constexpr double cexp_taylor(double r) {
    double s = 1.0, term = 1.0;
    for (int i = 1; i < 18; ++i) { term *= r / (double)i; s += term; }
    return s;
}
constexpr double cexp(double x) {             // |x| < 45
    const double LN2 = 0.69314718055994530942;
    const int n = (int)(x / LN2 + (x >= 0.0 ? 0.5 : -0.5));
    const double r = x - (double)n * LN2;
    double e = cexp_taylor(r);
    if (n >= 0) { for (int i = 0; i < n;  ++i) e *= 2.0; }
    else        { for (int i = 0; i < -n; ++i) e *= 0.5; }
    return e;
}
struct WTab {
    float w[STEPS];
    constexpr WTab() : w() {
        const double d = 2.2 / 63.0;
        for (int j = 0; j < STEPS; ++j) {
            const double z = 8.0 * d * (double)(111 - j);   // sigmoid argument
            w[j] = (float)(1.0 / ((1.0 + cexp(-z)) * 65536.0));
        }
    }
};
constexpr WTab WT;   // WT.w[j] folds as inline literals in unrolled fmas

// inclusive suffix sum within a 64-lane wave: x_i = sum_{k>=i} x_k
__device__ __forceinline__ float wave_suffix(float x, int lane) {
#pragma unroll
    for (int d = 1; d < 64; d <<= 1) {
        const float y = __shfl_down(x, d, 64);
        x += (lane + d < 64) ? y : 0.0f;
    }
    return x;
}

// uniform scalar lower_bound with +-1024 window around the expected position
// (batch ~ uniform random sorted: std of seg[b] <= ~160; window = 6+ sigma,
// validated by 2 loads, falls back to [0,n) -> unconditionally correct).
// readfirstlane pins indices to SGPR -> s_load chain, no vector gathers.
__device__ __forceinline__ int lower_scalar(const int* __restrict__ A, int n,
                                            int val) {
    const long long g = ((long long)val * (long long)n) >> 7;   // val*n/128
    int lo = (int)(g - 1024 > 0 ? g - 1024 : 0);
    int hi = (int)(g + 1024 < n ? g + 1024 : n);
    const bool okl = (lo == 0) || (A[__builtin_amdgcn_readfirstlane(lo - 1)] < val);
    const bool okh = (hi == n) || (A[__builtin_amdgcn_readfirstlane(hi)] >= val);
    if (!(okl && okh)) { lo = 0; hi = n; }
    while (hi > lo) {
        const int mid = (lo + hi) >> 1;
        const int key = A[__builtin_amdgcn_readfirstlane(mid)];
        if (key < val) lo = mid + 1; else hi = mid;
    }
    return lo;
}

__global__ __launch_bounds__(THREADS, 8) void ect_fused9_kernel(
    const float* __restrict__ x,      // [N,3]
    const float* __restrict__ v,      // [3,64]
    const int*   __restrict__ batch,  // [N] sorted 0..127
    float* __restrict__ out,          // [128,64,64]
    int n, float inv_d, float bias)
{
    __shared__ unsigned long long Hu[2 * TPB * ROW64];   // He rows | Ho rows, 8KiB

    const int tid  = threadIdx.x;
    const int wv   = tid >> 6;                   // wave 0..3
    const int lane = tid & 63;
    const int b    = blockIdx.x >> 4;            // / TQ
    const int tq   = blockIdx.x & (TQ - 1);

    // zero both histogram arrays (1024 u64 / 256 threads = 4 ds_write_b64)
    for (int i = tid; i < 2 * TPB * ROW64; i += THREADS) Hu[i] = 0ull;

    // segment bounds: two independent scalar s_load chains (~11 iters each),
    // overlapped with the zeroing and across the 8 resident blocks/CU
    const int s0 = lower_scalar(batch, n, b);
    const int s1 = lower_scalar(batch, n, b + 1);

    // deposit mapping: lane = (t_l, slot); block covers 64 nodes/iter
    const int t_l  = lane >> 4;                  // direction 0..3 within block
    const int slot = (lane & 15) + (wv << 4);    // node slot 0..63 across waves
    const int tbase = tq * TPB;
    const int t    = tbase + t_l;
    const float va = v[t], vb = v[64 + t], vc = v[128 + t];
    const int rowoff64 = t_l * ROW64;

    __syncthreads();                             // barrier 1: zero done

    // ---- phase 1: CIC deposit, ONE packed u64 atomic per (node,dir), ----
    // ---- 4-deep preload (256 nodes per outer iteration)              ----
    for (int base = s0; base < s1; base += 4 * 64) {
        float xs0[4], xs1[4], xs2[4];
        bool  ok[4];
#pragma unroll
        for (int k = 0; k < 4; ++k) {
            const int idx = base + (k << 6) + slot;
            ok[k] = (idx < s1);
            if (ok[k]) {
                const float3 xx = *(const float3*)(x + 3 * (size_t)idx);
                xs0[k] = xx.x; xs1[k] = xx.y; xs2[k] = xx.z;
            }
        }
#pragma unroll
        for (int k = 0; k < 4; ++k) {
            if (!ok[k]) continue;
            const float nh = fmaf(xs0[k], va, fmaf(xs1[k], vb, xs2[k] * vc));
            float bin = fmaf(nh, inv_d, bias);           // (nh - umin)/d
            bin = fminf(fmaxf(bin, 0.0f), 158.999f);     // tails saturate
            const float g0f = floorf(bin);
            const float fr  = bin - g0f;
            const int   a   = PAD + (int)g0f;            // 63..221
            const unsigned q1 = (unsigned)(fr * 65536.0f + 0.5f);
            const unsigned q0 = 65536u - q1;
            const unsigned long long val =
                (unsigned long long)q0 | ((unsigned long long)q1 << 32);
            // parity-staggered word: even a -> He[a/2], odd a -> Ho[(a-1)/2]
            const int w64 = (a >> 1) + rowoff64 + ((a & 1) ? HO_BASE64 : 0);
            atomicAdd(&Hu[w64], val);                    // ds_add_u64
        }
    }

    __syncthreads();                             // barrier 2: deposits done

    // ---- phase 1.5: per-wave OWN-ROW reconstruct (in place, u32->f32)  ----
    // H[a] = He32[a] + Ho32[a-1]. Chunk q: lane i reads word i+64q then
    // writes word i+64q (same lane, same word) -> chunk read/write sets are
    // pairwise disjoint -> no intra-phase hazard. Chunk 0 stays u32 (conv
    // never reads indices < J0=64); its value only feeds the register scan.
    float c[4];
    {
        const unsigned* He32 = (const unsigned*)Hu;
        const unsigned* Ho32 = (const unsigned*)(Hu + HO_BASE64);
        float* Hf = (float*)Hu;
        const int rb = wv * ROW32;               // wave owns row wv
#pragma unroll
        for (int q = 0; q < 4; ++q) {
            const int a = lane + 64 * q;
            unsigned s = He32[rb + a];
            if (a > 0) s += Ho32[rb + a - 1];    // folds to unconditional q>0
            c[q] = (float)s;
            if (q > 0) Hf[rb + a] = c[q];
        }
    }

    // ---- phase 1.75: register suffix scan; window is PURE-REGISTER ----
    // S[lane] = s0v, S[lane+64] = s1v  ->  sum_{j<64} H[lane+j] = s0v - s1v
    float tot23 = c[2] + c[3];
#pragma unroll
    for (int d = 1; d < 64; d <<= 1) tot23 += __shfl_xor(tot23, d, 64);
    const float s1v   = wave_suffix(c[1], lane) + tot23;
    const float carry = __shfl(s1v, 0, 64);
    const float s0v   = wave_suffix(c[0], lane) + carry;
    const float window = (s0v - s1v) * (1.0f / 65536.0f);

    __syncthreads();   // barrier 3: Hf f32 values visible to cross-lane conv

    // ---- phase 2: conv. wave wv -> direction row wv; lane -> r ----
    const float* H = (const float*)Hu + wv * ROW32 + lane;   // single base VGPR
    float a0 = window, a1 = 0.f;
#pragma unroll
    for (int j = J0; j < STEPS; j += 2) {
        a0 = fmaf(WT.w[j],     H[j],     a0);    // literal * ds_read2.lo
        a1 = fmaf(WT.w[j + 1], H[j + 1], a1);    // literal * ds_read2.hi
    }
    out[((size_t)b * 64 + tbase + wv) * 64 + lane] = a0 + a1;
}

extern "C" void kernel_launch(void* const* d_in, const int* in_sizes, int n_in,
                              void* d_out, int out_size, void* d_ws, size_t ws_size,
                              hipStream_t stream) {
    const float* x     = (const float*)d_in[0];
    const float* v     = (const float*)d_in[1];
    const int*   batch = (const int*)d_in[2];
    float*       out   = (float*)d_out;

    const int n = in_sizes[0] / 3;

    const double d = 2.2 / 63.0;
    const float inv_d = (float)(1.0 / d);          // 28.63636...
    const float bias  = 79.5f;                     // 31.5 + 48, exact

    hipLaunchKernelGGL(ect_fused9_kernel, dim3(BSEG * TQ), dim3(THREADS), 0,
                       stream, x, v, batch, out, n, inv_d, bias);
}

// Round 14
// 16.154 us; speedup vs baseline: 1.2567x; 1.1021x over previous
//
#include <hip/hip_runtime.h>
#include <math.h>

// ECT layer: ect[b,t,r] = sum_{n: batch[n]==b} sigmoid(8*(lin[r] - <x_n,v_t>))
// N=100000, D=3, T=64, R=64, B=128, lin = linspace(-1.1,1.1,64), d = 2.2/63.
//
// Validated core: CIC-deposit nh onto lin-aligned grid, convolve with
// compile-time sigmoid taps (literal fmas + ds_read2). r7: u32 LDS atomics
// (f32 LDS atomics = slow serial FP-RMW on gfx950, 4x). r11: extra dispatch
// costs ~3-5us -> single dispatch, scalar windowed binary search. r12:
// register suffix scan makes the 64 saturated taps free (window = s0v-s1v).
// r13: 16-bit-packed u32 atomics (half the DS bytes), integer bin math.
//
// r13 FAILURE root cause (fixed here): the integer-bin refactor dropped the
// +PAD(63) offset: bias stayed 79.5*256 and the clamp was [0,158*256+255],
// so every deposit landed 63 bins low (absmax 645). Fix: bias256 =
// (79.5+63)*256 = 36480, clamp = [63*256, 221*256+255] = [16128, 56831]
// (lower clamp at 16128, not 0: far-below-range nodes must land at a=63 to
// contribute ~1 to every r). Everything else identical to r13.

#define THREADS 256
#define TPB 4              // directions per block (1 per wave)
#define TQ  16             // blocks per point cloud
#define J0  64             // taps j<J0 == 1.0 exactly (window via scan)
#define STEPS 144          // real taps j in [J0,STEPS): 80 literal fmas
#define ROWW 128           // u32 words per row per parity array
#define HO_BASE (TPB * ROWW)            // Ho offset in u32 words (512)
#define HF_BASE (2 * TPB * ROWW)        // f32 H region offset (1024)
#define ROW32 256          // f32 elements per row in conv buffer
#define BSEG 128

#if __has_builtin(__builtin_amdgcn_fmed3f)
#define CLAMP(v, lo, hi) __builtin_amdgcn_fmed3f((v), (lo), (hi))
#else
#define CLAMP(v, lo, hi) fminf(fmaxf((v), (lo)), (hi))
#endif

// ---- compile-time sigmoid tap table (folds the 2^-8 quanta unscale) ----
constexpr double cexp_taylor(double r) {
    double s = 1.0, term = 1.0;
    for (int i = 1; i < 18; ++i) { term *= r / (double)i; s += term; }
    return s;
}
constexpr double cexp(double x) {
    const double LN2 = 0.69314718055994530942;
    const int n = (int)(x / LN2 + (x >= 0.0 ? 0.5 : -0.5));
    const double r = x - (double)n * LN2;
    double e = cexp_taylor(r);
    if (n >= 0) { for (int i = 0; i < n;  ++i) e *= 2.0; }
    else        { for (int i = 0; i < -n; ++i) e *= 0.5; }
    return e;
}
struct WTab {
    float w[STEPS];
    constexpr WTab() : w() {
        const double d = 2.2 / 63.0;
        for (int j = 0; j < STEPS; ++j) {
            const double z = 8.0 * d * (double)(111 - j);
            w[j] = (float)(1.0 / ((1.0 + cexp(-z)) * 256.0));
        }
    }
};
constexpr WTab WT;

// inclusive suffix sum within a 64-lane wave
__device__ __forceinline__ float wave_suffix(float x, int lane) {
#pragma unroll
    for (int d = 1; d < 64; d <<= 1) {
        const float y = __shfl_down(x, d, 64);
        x += (lane + d < 64) ? y : 0.0f;
    }
    return x;
}

// uniform scalar lower_bound, +-1024 window around expected position
// (validated by 2 loads; falls back to [0,n) -> unconditionally correct)
__device__ __forceinline__ int lower_scalar(const int* __restrict__ A, int n,
                                            int val) {
    const long long g = ((long long)val * (long long)n) >> 7;
    int lo = (int)(g - 1024 > 0 ? g - 1024 : 0);
    int hi = (int)(g + 1024 < n ? g + 1024 : n);
    const bool okl = (lo == 0) || (A[__builtin_amdgcn_readfirstlane(lo - 1)] < val);
    const bool okh = (hi == n) || (A[__builtin_amdgcn_readfirstlane(hi)] >= val);
    if (!(okl && okh)) { lo = 0; hi = n; }
    while (hi > lo) {
        const int mid = (lo + hi) >> 1;
        const int key = A[__builtin_amdgcn_readfirstlane(mid)];
        if (key < val) lo = mid + 1; else hi = mid;
    }
    return lo;
}

__global__ __launch_bounds__(THREADS, 8) void ect_fused11_kernel(
    const float* __restrict__ x,      // [N,3]
    const float* __restrict__ v,      // [3,64]
    const int*   __restrict__ batch,  // [N] sorted 0..127
    float* __restrict__ out,          // [128,64,64]
    int n, float inv_d256, float bias256)
{
    // [He: 512 u32][Ho: 512 u32][Hf: 1024 f32] = 8 KiB
    __shared__ unsigned Ls[2 * TPB * ROWW + TPB * ROW32];

    const int tid  = threadIdx.x;
    const int wv   = tid >> 6;
    const int lane = tid & 63;
    const int b    = blockIdx.x >> 4;
    const int tq   = blockIdx.x & (TQ - 1);

    // zero the packed histograms (1024 u32 = 4KB; Hf overwritten later)
    {
        unsigned long long* z = (unsigned long long*)Ls;
        for (int i = tid; i < TPB * ROWW; i += THREADS) z[i] = 0ull;
    }

    // segment bounds: two scalar s_load chains, overlapped with zeroing
    const int s0 = lower_scalar(batch, n, b);
    const int s1 = lower_scalar(batch, n, b + 1);

    // deposit mapping: lane = (t_l, slot)
    const int t_l  = lane >> 4;
    const int slot = (lane & 15) + (wv << 4);
    const int tbase = tq * TPB;
    const int t    = tbase + t_l;
    const float va = v[t], vb = v[64 + t], vc = v[128 + t];
    const int rowbyte = (t_l * ROWW) << 2;       // byte offset of He row t_l

    __syncthreads();                             // barrier 1: zero done

    // deposit one (node,dir): ~15 VALU + 1 ds_add_u32
    // a = ufix>>8 in [63,221]; pair (a,a+1): even a -> He[a>>1], odd -> Ho[a>>1]
#define DEPOSIT(x0, x1, x2)                                                   \
    {                                                                         \
        const float nh = fmaf((x0), va, fmaf((x1), vb, (x2) * vc));           \
        float bf = fmaf(nh, inv_d256, bias256);                               \
        bf = CLAMP(bf, 16128.0f, 56831.0f);      /* a in [63, 221] */         \
        const unsigned ufix = (unsigned)bf;      /* a=ufix>>8, fr8=ufix&255 */\
        const unsigned q1   = ufix & 255u;                                    \
        const unsigned val  = (q1 << 16) + (256u - q1);                       \
        const unsigned wbyte = ((ufix >> 7) & ~3u)        /* (a>>1)<<2 */     \
                             + ((ufix >> 6) & 4u ? (HO_BASE << 2) : 0u)       \
                             + rowbyte;                                       \
        atomicAdd((unsigned*)((char*)Ls + wbyte), val);                       \
    }

    // ---- phase 1: CIC deposit; full 256-node chunks guard-free + tail ----
    {
        const int len = s1 - s0;
        const int nfull = len >> 8;
        int base = s0;
        for (int c = 0; c < nfull; ++c, base += 256) {
            float xs[4][3];
#pragma unroll
            for (int k = 0; k < 4; ++k) {
                const float3 xx = *(const float3*)(x + 3 * (size_t)(base + (k << 6) + slot));
                xs[k][0] = xx.x; xs[k][1] = xx.y; xs[k][2] = xx.z;
            }
#pragma unroll
            for (int k = 0; k < 4; ++k) DEPOSIT(xs[k][0], xs[k][1], xs[k][2]);
        }
        for (; base < s1; base += 64) {
            const int idx = base + slot;
            if (idx < s1) {
                const float3 xx = *(const float3*)(x + 3 * (size_t)idx);
                DEPOSIT(xx.x, xx.y, xx.z);
            }
        }
    }

    __syncthreads();                             // barrier 2: deposits done

    // ---- phase 1.5: reconstruct H (u16 halves -> f32), wave owns row wv ----
    // H[a] = He.half[a] + Ho.half[a-1]:
    //   a even: He[a>>1].lo + (a>0 ? Ho[(a>>1)-1].hi : 0)
    //   a odd : Ho[a>>1].lo + He[a>>1].hi
    float c[4];
    {
        const unsigned* He = Ls + wv * ROWW;
        const unsigned* Ho = Ls + HO_BASE + wv * ROWW;
        float* Hf = (float*)(Ls + HF_BASE) + wv * ROW32;
        const int par = lane & 1;
#pragma unroll
        for (int q = 0; q < 4; ++q) {
            const int a = lane + 64 * q;
            const unsigned heW = He[a >> 1];
            const unsigned he  = par ? (heW >> 16) : (heW & 0xFFFFu);
            unsigned ho = 0u;
            if (a > 0) {                          // uniform except lane0,q0
                const unsigned hoW = Ho[(a - 1) >> 1];
                ho = par ? (hoW & 0xFFFFu) : (hoW >> 16);
            }
            c[q] = (float)(he + ho);
            if (q > 0) Hf[a] = c[q];              // conv reads a in [64,208)
        }
    }

    // ---- phase 1.75: register suffix scan; 64-tap window in-register ----
    float tot23 = c[2] + c[3];
#pragma unroll
    for (int d = 1; d < 64; d <<= 1) tot23 += __shfl_xor(tot23, d, 64);
    const float s1v   = wave_suffix(c[1], lane) + tot23;
    const float carry = __shfl(s1v, 0, 64);
    const float s0v   = wave_suffix(c[0], lane) + carry;
    const float window = (s0v - s1v) * (1.0f / 256.0f);

    __syncthreads();   // barrier 3: Hf visible to cross-lane conv reads

    // ---- phase 2: conv, 80 literal-fma taps, 40 ds_read2 ----
    const float* H = (const float*)(Ls + HF_BASE) + wv * ROW32 + lane;
    float a0 = window, a1 = 0.f;
#pragma unroll
    for (int j = J0; j < STEPS; j += 2) {
        a0 = fmaf(WT.w[j],     H[j],     a0);
        a1 = fmaf(WT.w[j + 1], H[j + 1], a1);
    }
    out[((size_t)b * 64 + tbase + wv) * 64 + lane] = a0 + a1;
#undef DEPOSIT
}

extern "C" void kernel_launch(void* const* d_in, const int* in_sizes, int n_in,
                              void* d_out, int out_size, void* d_ws, size_t ws_size,
                              hipStream_t stream) {
    const float* x     = (const float*)d_in[0];
    const float* v     = (const float*)d_in[1];
    const int*   batch = (const int*)d_in[2];
    float*       out   = (float*)d_out;

    const int n = in_sizes[0] / 3;

    const double d = 2.2 / 63.0;
    const float inv_d256 = (float)(256.0 / d);     // bin scale 256
    const float bias256  = (79.5f + 63.0f) * 256.0f;   // = 36480: pad included

    hipLaunchKernelGGL(ect_fused11_kernel, dim3(BSEG * TQ), dim3(THREADS), 0,
                       stream, x, v, batch, out, n, inv_d256, bias256);
}